// Round 6
// baseline (133.897 us; speedup 1.0000x reference)
//
#include <hip/hip_runtime.h>

#define F 128
#define S 25
#define CH 4      // column chunks
#define CW 32     // cols per chunk (64 B bf16 rows)

typedef __attribute__((ext_vector_type(8))) short bf16x8;
typedef __attribute__((ext_vector_type(4))) float f32x4;
typedef __attribute__((ext_vector_type(2))) float f32x2;

// round-to-nearest-even f32 -> bf16 bits
__device__ __forceinline__ ushort f2bf(float f) {
    uint u = __float_as_uint(f);
    return (ushort)((u + 0x7FFFu + ((u >> 16) & 1u)) >> 16);
}
__device__ __forceinline__ float bf_lo(uint v) { return __uint_as_float(v << 16); }
__device__ __forceinline__ float bf_hi(uint v) { return __uint_as_float(v & 0xFFFF0000u); }

__device__ __forceinline__ void acc8(float* a, const uint4& v) {
    a[0] += bf_lo(v.x); a[1] += bf_hi(v.x);
    a[2] += bf_lo(v.y); a[3] += bf_hi(v.y);
    a[4] += bf_lo(v.z); a[5] += bf_hi(v.z);
    a[6] += bf_lo(v.w); a[7] += bf_hi(v.w);
}

// neighbor_idx may arrive as int32 or int64. int64 LE with values < 2^31 has
// all odd dwords zero. Deterministic data probe.
__device__ __forceinline__ bool idx_is_i64(const int* __restrict__ p) {
    return (p[1] | p[3] | p[5] | p[7]) == 0;
}
__device__ __forceinline__ int load_idx(const int* __restrict__ p, size_t i, bool is64) {
    return is64 ? p[2 * i] : p[i];
}

// ---------------------------------------------------------------------------
// K0a: compact neighbor_idx to int32 (idx re-streamed CH x in K2)
// ---------------------------------------------------------------------------
__global__ __launch_bounds__(256) void compact_idx(
    const int* __restrict__ src, int* __restrict__ dst, int M)
{
    const bool is64 = idx_is_i64(src);
    int e = blockIdx.x * 256 + threadIdx.x;
    if (e < M) dst[e] = load_idx(src, (size_t)e, is64);
}

// ---------------------------------------------------------------------------
// K0b: pack W into MFMA B-fragment order ONCE (32 KB). K1 blocks then load it
// linearly instead of each redoing 16K strided scalar loads + f2bf.
// WFg[((kt*8+nt)*64 + lane)*8 + b] = bf16(W[kt*32 + 8*(lane>>4) + b][nt*16 + (lane&15)])
// ---------------------------------------------------------------------------
__global__ __launch_bounds__(256) void pack_W(
    const float* __restrict__ W, ushort* __restrict__ WFg)
{
    const int id = blockIdx.x * 256 + threadIdx.x;   // 0..2047
    if (id >= 4 * 8 * 64) return;
    const int l  = id & 63;
    const int nt = (id >> 6) & 7;
    const int kt = id >> 9;
    const int k0 = kt * 32 + (l >> 4) * 8;
    const int nn = nt * 16 + (l & 15);
    bf16x8 fr;
    #pragma unroll
    for (int b = 0; b < 8; ++b)
        fr[b] = (short)f2bf(W[(size_t)(k0 + b) * F + nn]);
    *(bf16x8*)(WFg + (size_t)id * 8) = fr;
}

// ---------------------------------------------------------------------------
// K1: y = bf16(x) @ bf16(W) via v_mfma_f32_16x16x32_bf16 (fp32 accum).
// CHUNKED=1 writes K2's chunk layout, else row-major.
// Layouts (learn_hip m89/m91): A row=lane&15, k=8*(lane>>4)+b;
//                              D col=lane&15, row=4*(lane>>4)+reg.
// ---------------------------------------------------------------------------
template <int CHUNKED>
__global__ __launch_bounds__(256) void gemm_xw_bf16(
    const float* __restrict__ x, const ushort* __restrict__ WFg,
    ushort* __restrict__ y, int N)
{
    __shared__ ushort WF[4][8][64][8];   // 32 KB

    const int tid  = threadIdx.x;
    const int lane = tid & 63;
    const int wid  = tid >> 6;

    // linear coalesced copy of the pre-packed fragment image (16 B/lane)
    {
        const bf16x8* src = (const bf16x8*)WFg;
        bf16x8* dst = (bf16x8*)&WF[0][0][0][0];
        #pragma unroll
        for (int i = 0; i < 8; ++i)
            dst[tid + 256 * i] = src[tid + 256 * i];
    }
    __syncthreads();

    const int n0 = blockIdx.x * 64 + wid * 16;
    const int arow = n0 + (lane & 15);
    const int arow_c = arow < N ? arow : N - 1;
    const float* xrow = x + (size_t)arow_c * F + (lane >> 4) * 8;

    f32x4 acc[8];
    #pragma unroll
    for (int nt = 0; nt < 8; ++nt) acc[nt] = (f32x4){0.f, 0.f, 0.f, 0.f};

    #pragma unroll
    for (int kt = 0; kt < 4; ++kt) {
        float4 a0 = *(const float4*)(xrow + kt * 32);
        float4 a1 = *(const float4*)(xrow + kt * 32 + 4);
        bf16x8 af;
        af[0] = (short)f2bf(a0.x); af[1] = (short)f2bf(a0.y);
        af[2] = (short)f2bf(a0.z); af[3] = (short)f2bf(a0.w);
        af[4] = (short)f2bf(a1.x); af[5] = (short)f2bf(a1.y);
        af[6] = (short)f2bf(a1.z); af[7] = (short)f2bf(a1.w);
        #pragma unroll
        for (int nt = 0; nt < 8; ++nt) {
            bf16x8 bf = *(const bf16x8*)&WF[kt][nt][lane][0];
            acc[nt] = __builtin_amdgcn_mfma_f32_16x16x32_bf16(af, bf, acc[nt], 0, 0, 0);
        }
    }

    const int drow0 = n0 + (lane >> 4) * 4;
    const int dcol  = lane & 15;
    #pragma unroll
    for (int nt = 0; nt < 8; ++nt) {
        #pragma unroll
        for (int r = 0; r < 4; ++r) {
            const int row = drow0 + r;
            if (row < N) {
                if (CHUNKED) {
                    // global col = nt*16 + dcol; chunk = nt>>1
                    y[((size_t)(nt >> 1) * N + row) * CW + (nt & 1) * 16 + dcol] = f2bf(acc[nt][r]);
                } else {
                    y[(size_t)row * F + nt * 16 + dcol] = f2bf(acc[nt][r]);
                }
            }
        }
    }
}

// ---------------------------------------------------------------------------
// K2: chunked gather-average, CW=32 (64 B rows), dwordx4 gathers.
// chunk = blockIdx & 3 rides HW round-robin block->XCD mapping.
// Block = 64 nodes; each wave = 16 nodes x 4 lanes (lane j covers 16 B of the
// 64 B row) -> one uint4 load per (node, neighbor): 0.65M instrs total.
// Values batched 13+12 to bound VGPR; idx staged in LDS; idx/out nontemporal.
// ---------------------------------------------------------------------------
__global__ __launch_bounds__(256) void gather_chunked(
    const ushort* __restrict__ y, const int* __restrict__ idx32,
    const float* __restrict__ bias, float* __restrict__ out, int N)
{
    __shared__ int IDX[64 * S];

    const int tid   = threadIdx.x;
    const int chunk = blockIdx.x & (CH - 1);
    const int tile  = blockIdx.x >> 2;
    const int nbase = tile * 64;
    const long total = (long)N * S;

    for (int e = tid; e < 64 * S; e += 256) {
        long p = (long)nbase * S + e;
        IDX[e] = (p < total) ? __builtin_nontemporal_load(&idx32[p]) : 0;
    }
    __syncthreads();

    const int lane = tid & 63, wave = tid >> 6;
    const int g = lane >> 2, j = lane & 3;        // 16 rows x 4 lanes
    const int nl = wave * 16 + g;                 // node within tile
    const int n  = nbase + nl;
    const int nc = n < N ? n : 0;
    const float inv = 1.0f / (float)(S + 1);
    const char* ycb = (const char*)(y + (size_t)chunk * N * CW);
    const int joff = j << 4;

    float acc[8];
    {   // self row
        uint4 v = *(const uint4*)(ycb + (((uint)nc) << 6) + joff);
        acc[0] = bf_lo(v.x); acc[1] = bf_hi(v.x);
        acc[2] = bf_lo(v.y); acc[3] = bf_hi(v.y);
        acc[4] = bf_lo(v.z); acc[5] = bf_hi(v.z);
        acc[6] = bf_lo(v.w); acc[7] = bf_hi(v.w);
    }

    uint4 v[13];
    #pragma unroll
    for (int s = 0; s < 13; ++s) {
        const int id = IDX[nl * S + s];
        v[s] = *(const uint4*)(ycb + (((uint)id) << 6) + joff);
    }
    #pragma unroll
    for (int s = 0; s < 13; ++s) acc8(acc, v[s]);

    #pragma unroll
    for (int s = 0; s < 12; ++s) {
        const int id = IDX[nl * S + 13 + s];
        v[s] = *(const uint4*)(ycb + (((uint)id) << 6) + joff);
    }
    #pragma unroll
    for (int s = 0; s < 12; ++s) acc8(acc, v[s]);

    if (n < N) {
        const float* bp = bias + chunk * CW + j * 8;
        float* op = out + (size_t)n * F + chunk * CW + j * 8;
        f32x4 o0 = {acc[0] * inv + bp[0], acc[1] * inv + bp[1],
                    acc[2] * inv + bp[2], acc[3] * inv + bp[3]};
        f32x4 o1 = {acc[4] * inv + bp[4], acc[5] * inv + bp[5],
                    acc[6] * inv + bp[6], acc[7] * inv + bp[7]};
        __builtin_nontemporal_store(o0, (f32x4*)op);
        __builtin_nontemporal_store(o1, (f32x4*)(op + 4));
    }
}

// ---------------------------------------------------------------------------
// Fallback A (ws fits y + WF): flat gather on row-major bf16 y.
// ---------------------------------------------------------------------------
__global__ __launch_bounds__(256) void gather_agg_bf16(
    const ushort* __restrict__ y, const int* __restrict__ nbr,
    const float* __restrict__ bias, float* __restrict__ out, int N)
{
    const int lane = threadIdx.x & 63;
    const int wid  = threadIdx.x >> 6;
    const bool is64 = idx_is_i64(nbr);
    const float2 bb = ((const float2*)bias)[lane];
    const float inv = 1.0f / (float)(S + 1);
    const int nw = gridDim.x * 4;
    const uint* yw = (const uint*)y;

    for (int n = blockIdx.x * 4 + wid; n < N; n += nw) {
        const int nu = __builtin_amdgcn_readfirstlane(n);
        int ids[S];
        #pragma unroll
        for (int s = 0; s < S; ++s)
            ids[s] = load_idx(nbr, (size_t)nu * S + s, is64);
        uint vs[S];
        #pragma unroll
        for (int s = 0; s < S; ++s)
            vs[s] = yw[(size_t)ids[s] * 64 + lane];
        const uint v0 = yw[(size_t)nu * 64 + lane];
        float ax = bf_lo(v0), ay = bf_hi(v0);
        #pragma unroll
        for (int s = 0; s < S; ++s) { ax += bf_lo(vs[s]); ay += bf_hi(vs[s]); }
        float2 o;
        o.x = ax * inv + bb.x;
        o.y = ay * inv + bb.y;
        ((float2*)(out + (size_t)nu * F))[lane] = o;
    }
}

// ---------------------------------------------------------------------------
// Fallback B (tiny ws): fused fp32 gather+GEMM.
// ---------------------------------------------------------------------------
__global__ __launch_bounds__(256) void fused_fallback_kernel(
    const float* __restrict__ x, const int* __restrict__ nbr,
    const float* __restrict__ W, const float* __restrict__ bias,
    float* __restrict__ out, int N)
{
    __shared__ float aggs[4][F];
    const int lane = threadIdx.x & 63;
    const int wid  = threadIdx.x >> 6;
    const bool is64 = idx_is_i64(nbr);
    const float inv = 1.0f / (float)(S + 1);
    const int stride = gridDim.x * 4;

    for (int base = blockIdx.x * 4; base < N; base += stride) {
        int n = base + wid;
        bool act = n < N;
        float2 acc = make_float2(0.f, 0.f);
        if (act) {
            acc = ((const float2*)(x + (size_t)n * F))[lane];
            for (int s = 0; s < S; ++s) {
                int id = load_idx(nbr, (size_t)n * S + s, is64);
                float2 v = ((const float2*)(x + (size_t)id * F))[lane];
                acc.x += v.x; acc.y += v.y;
            }
        }
        aggs[wid][2 * lane]     = acc.x * inv;
        aggs[wid][2 * lane + 1] = acc.y * inv;
        __syncthreads();
        if (act) {
            float o0 = bias[lane], o1 = bias[lane + 64];
            for (int k = 0; k < F; ++k) {
                float a = aggs[wid][k];
                o0 += a * W[k * F + lane];
                o1 += a * W[k * F + lane + 64];
            }
            out[(size_t)n * F + lane]      = o0;
            out[(size_t)n * F + lane + 64] = o1;
        }
        __syncthreads();
    }
}

extern "C" void kernel_launch(void* const* d_in, const int* in_sizes, int n_in,
                              void* d_out, int out_size, void* d_ws, size_t ws_size,
                              hipStream_t stream) {
    const float* x    = (const float*)d_in[0];
    const int*   nbr  = (const int*)d_in[1];
    const float* W    = (const float*)d_in[2];
    const float* bias = (const float*)d_in[3];
    float* out = (float*)d_out;
    const int N = in_sizes[0] / F;                 // 100000
    const int M = N * S;                           // 2.5M edges

    const size_t y_bytes   = (size_t)N * F * sizeof(ushort);   // 25.6 MB
    const size_t idx_bytes = (size_t)M * sizeof(int);          // 10 MB
    const size_t wf_bytes  = (size_t)4 * 8 * 64 * 8 * sizeof(ushort);  // 32 KB

    if (ws_size >= y_bytes + idx_bytes + wf_bytes) {
        ushort* y    = (ushort*)d_ws;
        int*   idx32 = (int*)((char*)d_ws + y_bytes);
        ushort* WFg  = (ushort*)((char*)d_ws + y_bytes + idx_bytes);
        compact_idx<<<(M + 255) / 256, 256, 0, stream>>>(nbr, idx32, M);
        pack_W<<<8, 256, 0, stream>>>(W, WFg);
        gemm_xw_bf16<1><<<(N + 63) / 64, 256, 0, stream>>>(x, WFg, y, N);
        const int tiles = (N + 63) / 64;           // 1563
        gather_chunked<<<tiles * CH, 256, 0, stream>>>(y, idx32, bias, out, N);
    } else if (ws_size >= y_bytes + wf_bytes) {
        ushort* y   = (ushort*)d_ws;
        ushort* WFg = (ushort*)((char*)d_ws + y_bytes);
        pack_W<<<8, 256, 0, stream>>>(W, WFg);
        gemm_xw_bf16<0><<<(N + 63) / 64, 256, 0, stream>>>(x, WFg, y, N);
        gather_agg_bf16<<<2048, 256, 0, stream>>>(y, nbr, bias, out, N);
    } else {
        fused_fallback_kernel<<<2048, 256, 0, stream>>>(x, nbr, W, bias, out, N);
    }
}

// Round 7
// 115.139 us; speedup vs baseline: 1.1629x; 1.1629x over previous
//
#include <hip/hip_runtime.h>

#define F 128
#define S 25
#define CH 4      // column chunks
#define CW 32     // cols per chunk (64 B bf16 rows)

typedef __attribute__((ext_vector_type(8))) short bf16x8;
typedef __attribute__((ext_vector_type(4))) float f32x4;

// round-to-nearest-even f32 -> bf16 bits
__device__ __forceinline__ ushort f2bf(float f) {
    uint u = __float_as_uint(f);
    return (ushort)((u + 0x7FFFu + ((u >> 16) & 1u)) >> 16);
}
__device__ __forceinline__ float bf_lo(uint v) { return __uint_as_float(v << 16); }
__device__ __forceinline__ float bf_hi(uint v) { return __uint_as_float(v & 0xFFFF0000u); }

// neighbor_idx may arrive as int32 or int64. int64 LE with values < 2^31 has
// all odd dwords zero. Deterministic data probe.
__device__ __forceinline__ bool idx_is_i64(const int* __restrict__ p) {
    return (p[1] | p[3] | p[5] | p[7]) == 0;
}
__device__ __forceinline__ int load_idx(const int* __restrict__ p, size_t i, bool is64) {
    return is64 ? p[2 * i] : p[i];
}

// ---------------------------------------------------------------------------
// K0a: compact neighbor_idx to int32 (idx re-streamed CH x in K2)
// ---------------------------------------------------------------------------
__global__ __launch_bounds__(256) void compact_idx(
    const int* __restrict__ src, int* __restrict__ dst, int M)
{
    const bool is64 = idx_is_i64(src);
    int e = blockIdx.x * 256 + threadIdx.x;
    if (e < M) dst[e] = load_idx(src, (size_t)e, is64);
}

// ---------------------------------------------------------------------------
// K0b: pack W into MFMA B-fragment order ONCE (32 KB).
// WFg[((kt*8+nt)*64 + lane)*8 + b] = bf16(W[kt*32 + 8*(lane>>4) + b][nt*16 + (lane&15)])
// ---------------------------------------------------------------------------
__global__ __launch_bounds__(256) void pack_W(
    const float* __restrict__ W, ushort* __restrict__ WFg)
{
    const int id = blockIdx.x * 256 + threadIdx.x;   // 0..2047
    if (id >= 4 * 8 * 64) return;
    const int l  = id & 63;
    const int nt = (id >> 6) & 7;
    const int kt = id >> 9;
    const int k0 = kt * 32 + (l >> 4) * 8;
    const int nn = nt * 16 + (l & 15);
    bf16x8 fr;
    #pragma unroll
    for (int b = 0; b < 8; ++b)
        fr[b] = (short)f2bf(W[(size_t)(k0 + b) * F + nn]);
    *(bf16x8*)(WFg + (size_t)id * 8) = fr;
}

// ---------------------------------------------------------------------------
// K1: y = bf16(x) @ bf16(W) via v_mfma_f32_16x16x32_bf16 (fp32 accum).
// CHUNKED=1 writes K2's chunk layout, else row-major.
// Layouts (learn_hip m89/m91): A row=lane&15, k=8*(lane>>4)+b;
//                              D col=lane&15, row=4*(lane>>4)+reg.
// ---------------------------------------------------------------------------
template <int CHUNKED>
__global__ __launch_bounds__(256) void gemm_xw_bf16(
    const float* __restrict__ x, const ushort* __restrict__ WFg,
    ushort* __restrict__ y, int N)
{
    __shared__ ushort WF[4][8][64][8];   // 32 KB

    const int tid  = threadIdx.x;
    const int lane = tid & 63;
    const int wid  = tid >> 6;

    // linear coalesced copy of the pre-packed fragment image (16 B/lane)
    {
        const bf16x8* src = (const bf16x8*)WFg;
        bf16x8* dst = (bf16x8*)&WF[0][0][0][0];
        #pragma unroll
        for (int i = 0; i < 8; ++i)
            dst[tid + 256 * i] = src[tid + 256 * i];
    }
    __syncthreads();

    const int n0 = blockIdx.x * 64 + wid * 16;
    const int arow = n0 + (lane & 15);
    const int arow_c = arow < N ? arow : N - 1;
    const float* xrow = x + (size_t)arow_c * F + (lane >> 4) * 8;

    f32x4 acc[8];
    #pragma unroll
    for (int nt = 0; nt < 8; ++nt) acc[nt] = (f32x4){0.f, 0.f, 0.f, 0.f};

    #pragma unroll
    for (int kt = 0; kt < 4; ++kt) {
        float4 a0 = *(const float4*)(xrow + kt * 32);
        float4 a1 = *(const float4*)(xrow + kt * 32 + 4);
        bf16x8 af;
        af[0] = (short)f2bf(a0.x); af[1] = (short)f2bf(a0.y);
        af[2] = (short)f2bf(a0.z); af[3] = (short)f2bf(a0.w);
        af[4] = (short)f2bf(a1.x); af[5] = (short)f2bf(a1.y);
        af[6] = (short)f2bf(a1.z); af[7] = (short)f2bf(a1.w);
        #pragma unroll
        for (int nt = 0; nt < 8; ++nt) {
            bf16x8 bf = *(const bf16x8*)&WF[kt][nt][lane][0];
            acc[nt] = __builtin_amdgcn_mfma_f32_16x16x32_bf16(af, bf, acc[nt], 0, 0, 0);
        }
    }

    const int drow0 = n0 + (lane >> 4) * 4;
    const int dcol  = lane & 15;
    #pragma unroll
    for (int nt = 0; nt < 8; ++nt) {
        #pragma unroll
        for (int r = 0; r < 4; ++r) {
            const int row = drow0 + r;
            if (row < N) {
                if (CHUNKED) {
                    y[((size_t)(nt >> 1) * N + row) * CW + (nt & 1) * 16 + dcol] = f2bf(acc[nt][r]);
                } else {
                    y[(size_t)row * F + nt * 16 + dcol] = f2bf(acc[nt][r]);
                }
            }
        }
    }
}

// ---------------------------------------------------------------------------
// K2: chunked gather-average, CW=32 (64 B rows), dwordx2 gathers.
// chunk = blockIdx & 3 rides HW round-robin block->XCD mapping.
// Block = 64 nodes; wave = 8 rows x 8 lanes per instr (lane j covers 8 B of
// the 64 B row), 2 octs of 8 nodes -> 1.3M wave-instrs total.
// 26 loads in flight per oct; base+voffset addressing keeps VGPR ~70.
// ---------------------------------------------------------------------------
__global__ __launch_bounds__(256) void gather_chunked(
    const ushort* __restrict__ y, const int* __restrict__ idx32,
    const float* __restrict__ bias, float* __restrict__ out, int N)
{
    __shared__ int IDX[64 * S];

    const int tid   = threadIdx.x;
    const int chunk = blockIdx.x & (CH - 1);
    const int tile  = blockIdx.x >> 2;
    const int nbase = tile * 64;
    const long total = (long)N * S;

    for (int e = tid; e < 64 * S; e += 256) {
        long p = (long)nbase * S + e;
        IDX[e] = (p < total) ? __builtin_nontemporal_load(&idx32[p]) : 0;
    }
    __syncthreads();

    const int lane = tid & 63, wave = tid >> 6;
    const int g = lane >> 3, j = lane & 7;        // 8 rows x 8 lanes
    const float inv = 1.0f / (float)(S + 1);
    const char* ycb = (const char*)(y + (size_t)chunk * N * CW);
    const uint joff = (uint)(j << 3);             // byte offset within 64 B row
    const f32x4 bb = *(const f32x4*)(bias + chunk * CW + 4 * j);

    #pragma unroll
    for (int oct = 0; oct < 2; ++oct) {
        const int nl = wave * 16 + oct * 8 + g;   // node within tile
        const int n  = nbase + nl;
        const int nc = n < N ? n : 0;

        uint2 v[26];
        v[25] = *(const uint2*)(ycb + (((uint)nc) << 6) + joff);   // self
        #pragma unroll
        for (int s = 0; s < S; ++s) {
            const uint id = (uint)IDX[nl * S + s];
            v[s] = *(const uint2*)(ycb + (id << 6) + joff);
        }

        float a0 = 0.f, a1 = 0.f, a2 = 0.f, a3 = 0.f;
        #pragma unroll
        for (int s = 0; s < 26; ++s) {
            a0 += bf_lo(v[s].x); a1 += bf_hi(v[s].x);
            a2 += bf_lo(v[s].y); a3 += bf_hi(v[s].y);
        }

        if (n < N) {
            f32x4 o = {a0 * inv + bb.x, a1 * inv + bb.y,
                       a2 * inv + bb.z, a3 * inv + bb.w};
            __builtin_nontemporal_store(
                o, (f32x4*)(out + (size_t)n * F + chunk * CW + 4 * j));
        }
    }
}

// ---------------------------------------------------------------------------
// Fallback A (ws fits y + WF): flat gather on row-major bf16 y.
// ---------------------------------------------------------------------------
__global__ __launch_bounds__(256) void gather_agg_bf16(
    const ushort* __restrict__ y, const int* __restrict__ nbr,
    const float* __restrict__ bias, float* __restrict__ out, int N)
{
    const int lane = threadIdx.x & 63;
    const int wid  = threadIdx.x >> 6;
    const bool is64 = idx_is_i64(nbr);
    const float2 bb = ((const float2*)bias)[lane];
    const float inv = 1.0f / (float)(S + 1);
    const int nw = gridDim.x * 4;
    const uint* yw = (const uint*)y;

    for (int n = blockIdx.x * 4 + wid; n < N; n += nw) {
        const int nu = __builtin_amdgcn_readfirstlane(n);
        int ids[S];
        #pragma unroll
        for (int s = 0; s < S; ++s)
            ids[s] = load_idx(nbr, (size_t)nu * S + s, is64);
        uint vs[S];
        #pragma unroll
        for (int s = 0; s < S; ++s)
            vs[s] = yw[(size_t)ids[s] * 64 + lane];
        const uint v0 = yw[(size_t)nu * 64 + lane];
        float ax = bf_lo(v0), ay = bf_hi(v0);
        #pragma unroll
        for (int s = 0; s < S; ++s) { ax += bf_lo(vs[s]); ay += bf_hi(vs[s]); }
        float2 o;
        o.x = ax * inv + bb.x;
        o.y = ay * inv + bb.y;
        ((float2*)(out + (size_t)nu * F))[lane] = o;
    }
}

// ---------------------------------------------------------------------------
// Fallback B (tiny ws): fused fp32 gather+GEMM.
// ---------------------------------------------------------------------------
__global__ __launch_bounds__(256) void fused_fallback_kernel(
    const float* __restrict__ x, const int* __restrict__ nbr,
    const float* __restrict__ W, const float* __restrict__ bias,
    float* __restrict__ out, int N)
{
    __shared__ float aggs[4][F];
    const int lane = threadIdx.x & 63;
    const int wid  = threadIdx.x >> 6;
    const bool is64 = idx_is_i64(nbr);
    const float inv = 1.0f / (float)(S + 1);
    const int stride = gridDim.x * 4;

    for (int base = blockIdx.x * 4; base < N; base += stride) {
        int n = base + wid;
        bool act = n < N;
        float2 acc = make_float2(0.f, 0.f);
        if (act) {
            acc = ((const float2*)(x + (size_t)n * F))[lane];
            for (int s = 0; s < S; ++s) {
                int id = load_idx(nbr, (size_t)n * S + s, is64);
                float2 v = ((const float2*)(x + (size_t)id * F))[lane];
                acc.x += v.x; acc.y += v.y;
            }
        }
        aggs[wid][2 * lane]     = acc.x * inv;
        aggs[wid][2 * lane + 1] = acc.y * inv;
        __syncthreads();
        if (act) {
            float o0 = bias[lane], o1 = bias[lane + 64];
            for (int k = 0; k < F; ++k) {
                float a = aggs[wid][k];
                o0 += a * W[k * F + lane];
                o1 += a * W[k * F + lane + 64];
            }
            out[(size_t)n * F + lane]      = o0;
            out[(size_t)n * F + lane + 64] = o1;
        }
        __syncthreads();
    }
}

extern "C" void kernel_launch(void* const* d_in, const int* in_sizes, int n_in,
                              void* d_out, int out_size, void* d_ws, size_t ws_size,
                              hipStream_t stream) {
    const float* x    = (const float*)d_in[0];
    const int*   nbr  = (const int*)d_in[1];
    const float* W    = (const float*)d_in[2];
    const float* bias = (const float*)d_in[3];
    float* out = (float*)d_out;
    const int N = in_sizes[0] / F;                 // 100000
    const int M = N * S;                           // 2.5M edges

    const size_t y_bytes   = (size_t)N * F * sizeof(ushort);   // 25.6 MB
    const size_t idx_bytes = (size_t)M * sizeof(int);          // 10 MB
    const size_t wf_bytes  = (size_t)4 * 8 * 64 * 8 * sizeof(ushort);  // 32 KB

    if (ws_size >= y_bytes + idx_bytes + wf_bytes) {
        ushort* y    = (ushort*)d_ws;
        int*   idx32 = (int*)((char*)d_ws + y_bytes);
        ushort* WFg  = (ushort*)((char*)d_ws + y_bytes + idx_bytes);
        compact_idx<<<(M + 255) / 256, 256, 0, stream>>>(nbr, idx32, M);
        pack_W<<<8, 256, 0, stream>>>(W, WFg);
        gemm_xw_bf16<1><<<(N + 63) / 64, 256, 0, stream>>>(x, WFg, y, N);
        const int tiles = (N + 63) / 64;           // 1563
        gather_chunked<<<tiles * CH, 256, 0, stream>>>(y, idx32, bias, out, N);
    } else if (ws_size >= y_bytes + wf_bytes) {
        ushort* y   = (ushort*)d_ws;
        ushort* WFg = (ushort*)((char*)d_ws + y_bytes);
        pack_W<<<8, 256, 0, stream>>>(W, WFg);
        gemm_xw_bf16<0><<<(N + 63) / 64, 256, 0, stream>>>(x, WFg, y, N);
        gather_agg_bf16<<<2048, 256, 0, stream>>>(y, nbr, bias, out, N);
    } else {
        fused_fallback_kernel<<<2048, 256, 0, stream>>>(x, nbr, W, bias, out, N);
    }
}

// Round 9
// 102.253 us; speedup vs baseline: 1.3095x; 1.1260x over previous
//
#include <hip/hip_runtime.h>

#define F 128
#define S 25
#define CH 2      // column chunks
#define CW 64     // cols per chunk (128 B bf16 rows -> 12.8 MB slice per chunk)

typedef __attribute__((ext_vector_type(8))) short bf16x8;
typedef __attribute__((ext_vector_type(4))) float f32x4;

// round-to-nearest-even f32 -> bf16 bits
__device__ __forceinline__ ushort f2bf(float f) {
    uint u = __float_as_uint(f);
    return (ushort)((u + 0x7FFFu + ((u >> 16) & 1u)) >> 16);
}
__device__ __forceinline__ float bf_lo(uint v) { return __uint_as_float(v << 16); }
__device__ __forceinline__ float bf_hi(uint v) { return __uint_as_float(v & 0xFFFF0000u); }

// neighbor_idx may arrive as int32 or int64. int64 LE with values < 2^31 has
// all odd dwords zero. Deterministic data probe.
__device__ __forceinline__ bool idx_is_i64(const int* __restrict__ p) {
    return (p[1] | p[3] | p[5] | p[7]) == 0;
}
__device__ __forceinline__ int load_idx(const int* __restrict__ p, size_t i, bool is64) {
    return is64 ? p[2 * i] : p[i];
}

// ---------------------------------------------------------------------------
// K0: pack W into MFMA B-fragment order ONCE (32 KB).
// WFg[((kt*8+nt)*64 + lane)*8 + b] = bf16(W[kt*32 + 8*(lane>>4) + b][nt*16 + (lane&15)])
// ---------------------------------------------------------------------------
__global__ __launch_bounds__(256) void pack_W(
    const float* __restrict__ W, ushort* __restrict__ WFg)
{
    const int id = blockIdx.x * 256 + threadIdx.x;   // 0..2047
    if (id >= 4 * 8 * 64) return;
    const int l  = id & 63;
    const int nt = (id >> 6) & 7;
    const int kt = id >> 9;
    const int k0 = kt * 32 + (l >> 4) * 8;
    const int nn = nt * 16 + (l & 15);
    bf16x8 fr;
    #pragma unroll
    for (int b = 0; b < 8; ++b)
        fr[b] = (short)f2bf(W[(size_t)(k0 + b) * F + nn]);
    *(bf16x8*)(WFg + (size_t)id * 8) = fr;
}

// ---------------------------------------------------------------------------
// K1: y = bf16(x) @ bf16(W) via v_mfma_f32_16x16x32_bf16 (fp32 accum).
// Epilogue: stage the block's 64x128 bf16 tile in LDS then write coalesced
// 16 B stores. FIX vs R8: Ytile row must include the wave offset wid*16
// (R8 wrote only rows 0-15, leaving 16-63 uninitialized -> NaN).
// Layouts (learn_hip m89/m91): A row=lane&15, k=8*(lane>>4)+b;
//                              D col=lane&15, row=4*(lane>>4)+reg.
// ---------------------------------------------------------------------------
template <int CHUNKED>
__global__ __launch_bounds__(256) void gemm_xw_bf16(
    const float* __restrict__ x, const ushort* __restrict__ WFg,
    ushort* __restrict__ y, int N)
{
    __shared__ __align__(16) ushort WF[4][8][64][8];   // 32 KB
    __shared__ __align__(16) ushort Ytile[64][136];    // 17.4 KB, pad keeps 16B align

    const int tid  = threadIdx.x;
    const int lane = tid & 63;
    const int wid  = tid >> 6;

    // linear coalesced copy of the pre-packed fragment image (16 B/lane)
    {
        const bf16x8* src = (const bf16x8*)WFg;
        bf16x8* dst = (bf16x8*)&WF[0][0][0][0];
        #pragma unroll
        for (int i = 0; i < 8; ++i)
            dst[tid + 256 * i] = src[tid + 256 * i];
    }
    __syncthreads();

    const int n0 = blockIdx.x * 64 + wid * 16;
    const int arow = n0 + (lane & 15);
    const int arow_c = arow < N ? arow : N - 1;
    const float* xrow = x + (size_t)arow_c * F + (lane >> 4) * 8;

    f32x4 acc[8];
    #pragma unroll
    for (int nt = 0; nt < 8; ++nt) acc[nt] = (f32x4){0.f, 0.f, 0.f, 0.f};

    #pragma unroll
    for (int kt = 0; kt < 4; ++kt) {
        float4 a0 = *(const float4*)(xrow + kt * 32);
        float4 a1 = *(const float4*)(xrow + kt * 32 + 4);
        bf16x8 af;
        af[0] = (short)f2bf(a0.x); af[1] = (short)f2bf(a0.y);
        af[2] = (short)f2bf(a0.z); af[3] = (short)f2bf(a0.w);
        af[4] = (short)f2bf(a1.x); af[5] = (short)f2bf(a1.y);
        af[6] = (short)f2bf(a1.z); af[7] = (short)f2bf(a1.w);
        #pragma unroll
        for (int nt = 0; nt < 8; ++nt) {
            bf16x8 bf = *(const bf16x8*)&WF[kt][nt][lane][0];
            acc[nt] = __builtin_amdgcn_mfma_f32_16x16x32_bf16(af, bf, acc[nt], 0, 0, 0);
        }
    }

    // stage D fragments into LDS; block-local row = wid*16 + (lane>>4)*4 + r
    const int lr0  = wid * 16 + (lane >> 4) * 4;
    const int dcol = lane & 15;
    #pragma unroll
    for (int nt = 0; nt < 8; ++nt) {
        #pragma unroll
        for (int r = 0; r < 4; ++r)
            Ytile[lr0 + r][nt * 16 + dcol] = f2bf(acc[nt][r]);
    }
    __syncthreads();

    // coalesced write-out: 1024 chunks of 16 B (64 rows x 16 segs)
    const int n0b = blockIdx.x * 64;
    #pragma unroll
    for (int i = 0; i < 4; ++i) {
        const int e   = i * 256 + tid;
        const int row = e >> 4, seg = e & 15;
        const int n   = n0b + row;
        if (n < N) {
            bf16x8 val = *(const bf16x8*)&Ytile[row][seg * 8];
            if (CHUNKED) {
                const int c = seg >> 3;              // global col = seg*8 -> chunk
                const int ccol = (seg & 7) * 8;
                *(bf16x8*)&y[((size_t)c * N + n) * CW + ccol] = val;
            } else {
                *(bf16x8*)&y[(size_t)n * F + seg * 8] = val;
            }
        }
    }
}

// ---------------------------------------------------------------------------
// K2: chunked gather-average, CW=64 (128 B rows), CH=2.
// chunk = blockIdx & 1 -> chunk c rides the HW round-robin onto XCDs
// {c, c+2, c+4, c+6}; 12.8 MB slice vs 16 MB aggregate L2.
// Wave = 4 rows x 16 lanes per access (lane j covers 8 B of the 128 B row).
// idx staged in LDS directly from the raw (int64 or int32) neighbor buffer.
// ---------------------------------------------------------------------------
__global__ __launch_bounds__(256) void gather_chunked(
    const ushort* __restrict__ y, const int* __restrict__ nbr,
    const float* __restrict__ bias, float* __restrict__ out, int N)
{
    __shared__ int IDX[64 * S];

    const int tid   = threadIdx.x;
    const int chunk = blockIdx.x & (CH - 1);
    const int tile  = blockIdx.x >> 1;
    const int nbase = tile * 64;
    const long total = (long)N * S;
    const bool is64 = idx_is_i64(nbr);

    if (is64) {
        for (int e = tid; e < 64 * S; e += 256) {
            long p = (long)nbase * S + e;
            IDX[e] = (p < total) ? __builtin_nontemporal_load(&nbr[2 * p]) : 0;
        }
    } else {
        for (int e = tid; e < 64 * S; e += 256) {
            long p = (long)nbase * S + e;
            IDX[e] = (p < total) ? __builtin_nontemporal_load(&nbr[p]) : 0;
        }
    }
    __syncthreads();

    const int lane = tid & 63, wave = tid >> 6;
    const int g = lane >> 4, j = lane & 15;       // 4 rows x 16 lanes
    const float inv = 1.0f / (float)(S + 1);
    const char* ycb = (const char*)(y + (size_t)chunk * N * CW);
    const uint joff = (uint)(j << 3);             // byte offset within 128 B row
    const f32x4 bb = *(const f32x4*)(bias + chunk * CW + 4 * j);

    #pragma unroll
    for (int q = 0; q < 4; ++q) {
        const int nl = wave * 16 + q * 4 + g;     // node within tile
        const int n  = nbase + nl;
        const int nc = n < N ? n : 0;

        uint2 v[26];
        v[25] = *(const uint2*)(ycb + (((uint)nc) << 7) + joff);   // self
        #pragma unroll
        for (int s = 0; s < S; ++s) {
            const uint id = (uint)IDX[nl * S + s];
            v[s] = *(const uint2*)(ycb + (id << 7) + joff);
        }

        float a0 = 0.f, a1 = 0.f, a2 = 0.f, a3 = 0.f;
        #pragma unroll
        for (int s = 0; s < 26; ++s) {
            a0 += bf_lo(v[s].x); a1 += bf_hi(v[s].x);
            a2 += bf_lo(v[s].y); a3 += bf_hi(v[s].y);
        }

        if (n < N) {
            f32x4 o = {a0 * inv + bb.x, a1 * inv + bb.y,
                       a2 * inv + bb.z, a3 * inv + bb.w};
            __builtin_nontemporal_store(
                o, (f32x4*)(out + (size_t)n * F + chunk * CW + 4 * j));
        }
    }
}

// ---------------------------------------------------------------------------
// Fallback (tiny ws): fused fp32 gather+GEMM.
// ---------------------------------------------------------------------------
__global__ __launch_bounds__(256) void fused_fallback_kernel(
    const float* __restrict__ x, const int* __restrict__ nbr,
    const float* __restrict__ W, const float* __restrict__ bias,
    float* __restrict__ out, int N)
{
    __shared__ float aggs[4][F];
    const int lane = threadIdx.x & 63;
    const int wid  = threadIdx.x >> 6;
    const bool is64 = idx_is_i64(nbr);
    const float inv = 1.0f / (float)(S + 1);
    const int stride = gridDim.x * 4;

    for (int base = blockIdx.x * 4; base < N; base += stride) {
        int n = base + wid;
        bool act = n < N;
        float2 acc = make_float2(0.f, 0.f);
        if (act) {
            acc = ((const float2*)(x + (size_t)n * F))[lane];
            for (int s = 0; s < S; ++s) {
                int id = load_idx(nbr, (size_t)n * S + s, is64);
                float2 v = ((const float2*)(x + (size_t)id * F))[lane];
                acc.x += v.x; acc.y += v.y;
            }
        }
        aggs[wid][2 * lane]     = acc.x * inv;
        aggs[wid][2 * lane + 1] = acc.y * inv;
        __syncthreads();
        if (act) {
            float o0 = bias[lane], o1 = bias[lane + 64];
            for (int k = 0; k < F; ++k) {
                float a = aggs[wid][k];
                o0 += a * W[k * F + lane];
                o1 += a * W[k * F + lane + 64];
            }
            out[(size_t)n * F + lane]      = o0;
            out[(size_t)n * F + lane + 64] = o1;
        }
        __syncthreads();
    }
}

extern "C" void kernel_launch(void* const* d_in, const int* in_sizes, int n_in,
                              void* d_out, int out_size, void* d_ws, size_t ws_size,
                              hipStream_t stream) {
    const float* x    = (const float*)d_in[0];
    const int*   nbr  = (const int*)d_in[1];
    const float* W    = (const float*)d_in[2];
    const float* bias = (const float*)d_in[3];
    float* out = (float*)d_out;
    const int N = in_sizes[0] / F;                 // 100000

    const size_t y_bytes  = (size_t)N * F * sizeof(ushort);              // 25.6 MB
    const size_t wf_bytes = (size_t)4 * 8 * 64 * 8 * sizeof(ushort);     // 32 KB

    if (ws_size >= y_bytes + wf_bytes) {
        ushort* y   = (ushort*)d_ws;
        ushort* WFg = (ushort*)((char*)d_ws + y_bytes);
        pack_W<<<8, 256, 0, stream>>>(W, WFg);
        const int tiles = (N + 63) / 64;           // 1563
        gemm_xw_bf16<1><<<tiles, 256, 0, stream>>>(x, WFg, y, N);
        gather_chunked<<<tiles * CH, 256, 0, stream>>>(y, nbr, bias, out, N);
    } else {
        fused_fallback_kernel<<<2048, 256, 0, stream>>>(x, nbr, W, bias, out, N);
    }
}